// Round 1
// baseline (465.156 us; speedup 1.0000x reference)
//
#include <hip/hip_runtime.h>
#include <hip/hip_bf16.h>

// Problem constants (B=8, T=4096, Din=Dout=256, WINDOW=2)
#define BDIM 8
#define TDIM 4096
#define DDIM 256
#define MDIM (BDIM * TDIM)   // 32768 rows
#define NCHUNK 64            // chunks along T for the parallel scan
#define LCHUNK (TDIM / NCHUNK) // 64 steps per chunk

__device__ __forceinline__ float sigmoid_(float x) {
    return 1.0f / (1.0f + __expf(-x));
}
__device__ __forceinline__ float tanh_(float x) {
    // tanh(x) = 2*sigmoid(2x) - 1
    return 2.0f / (1.0f + __expf(-2.0f * x)) - 1.0f;
}

// ---------------------------------------------------------------------------
// Kernel 1: fused window-conv GEMM for one gate per blockIdx.z.
//   gate[m, j] = bias[j] + sum_k x[m-1,k]*W[0,k,j] + x[m,k]*W[1,k,j]
// 64x64 output tile per block, 256 threads, 4x4 register micro-tile.
// z -> tanh -> zbuf ; f -> sigmoid -> fbuf ; o -> sigmoid -> d_out (staged)
// ---------------------------------------------------------------------------
__global__ __launch_bounds__(256) void gates_gemm(
    const float* __restrict__ x,
    const float* __restrict__ Wz, const float* __restrict__ Wf,
    const float* __restrict__ Wo,
    const float* __restrict__ bz, const float* __restrict__ bf,
    const float* __restrict__ bo,
    float* __restrict__ zbuf, float* __restrict__ fbuf,
    float* __restrict__ obuf)
{
    const int gate = blockIdx.z;
    const float* W    = (gate == 0) ? Wz : (gate == 1) ? Wf : Wo;
    const float* bias = (gate == 0) ? bz : (gate == 1) ? bf : bo;
    float* outp       = (gate == 0) ? zbuf : (gate == 1) ? fbuf : obuf;

    const int m0 = blockIdx.x * 64;
    const int n0 = blockIdx.y * 64;
    const int tid = threadIdx.x;
    const int tx = tid & 15;       // col group
    const int ty = tid >> 4;       // row group

    // LDS tiles: A transposed [k][m] (pad to 68 for bank spread, 16B-aligned
    // row stride 272B), B natural [k][n].
    __shared__ alignas(16) float As[16][68];
    __shared__ alignas(16) float Bs[16][64];

    float acc[4][4] = {};

    // A loader: thread -> (row lr, k quad lk); 64 rows x 16 k per step.
    const int lr = tid >> 2;        // 0..63
    const int lk = (tid & 3) * 4;   // 0,4,8,12
    // B loader: thread -> (k row bk, col quad bc); 16 k x 64 cols per step.
    const int bk = tid >> 4;        // 0..15
    const int bc = (tid & 15) * 4;  // 0..60

    const int m = m0 + lr;
    const int t = m & (TDIM - 1);

    for (int ph = 0; ph < 2; ++ph) {
        // ph=0 uses x[m-1] (zero at t==0) with W[0]; ph=1 uses x[m] with W[1]
        const bool valid = (ph == 1) || (t != 0);
        const float* Arow = x + (size_t)(m - 1 + ph) * DDIM;
        const float* Wp = W + (size_t)ph * DDIM * DDIM;

        for (int k0 = 0; k0 < DDIM; k0 += 16) {
            float4 av = valid ? *(const float4*)(Arow + k0 + lk)
                              : make_float4(0.f, 0.f, 0.f, 0.f);
            float4 bv = *(const float4*)(Wp + (size_t)(k0 + bk) * DDIM + n0 + bc);
            __syncthreads();
            As[lk + 0][lr] = av.x;
            As[lk + 1][lr] = av.y;
            As[lk + 2][lr] = av.z;
            As[lk + 3][lr] = av.w;
            *(float4*)(&Bs[bk][bc]) = bv;
            __syncthreads();

            #pragma unroll
            for (int kk = 0; kk < 16; ++kk) {
                float4 a4 = *(const float4*)(&As[kk][ty * 4]);
                float4 b4 = *(const float4*)(&Bs[kk][tx * 4]);
                float a_[4] = {a4.x, a4.y, a4.z, a4.w};
                float b_[4] = {b4.x, b4.y, b4.z, b4.w};
                #pragma unroll
                for (int i = 0; i < 4; ++i)
                    #pragma unroll
                    for (int j = 0; j < 4; ++j)
                        acc[i][j] += a_[i] * b_[j];
            }
        }
    }

    // Epilogue: bias + activation + coalesced float4 stores.
    const int col = n0 + tx * 4;
    float4 bia = *(const float4*)(bias + col);
    float bi_[4] = {bia.x, bia.y, bia.z, bia.w};
    #pragma unroll
    for (int i = 0; i < 4; ++i) {
        const int row = m0 + ty * 4 + i;
        float4 v;
        float r_[4];
        #pragma unroll
        for (int j = 0; j < 4; ++j) {
            float val = acc[i][j] + bi_[j];
            r_[j] = (gate == 0) ? tanh_(val) : sigmoid_(val);
        }
        v.x = r_[0]; v.y = r_[1]; v.z = r_[2]; v.w = r_[3];
        *(float4*)(outp + (size_t)row * DDIM + col) = v;
    }
}

// ---------------------------------------------------------------------------
// Kernel 2: scan pass 1 — per-chunk aggregates.
// c_t = f*c + (1-f)*z over LCHUNK steps starting from c=0; A = prod(f).
// thread -> (b, chunk, d); d fastest => coalesced wave loads.
// ---------------------------------------------------------------------------
__global__ __launch_bounds__(256) void scan_pass1(
    const float* __restrict__ zbuf, const float* __restrict__ fbuf,
    float* __restrict__ aggA, float* __restrict__ aggB)
{
    const int idx = blockIdx.x * 256 + threadIdx.x;  // (b*NCHUNK+chunk)*256 + d
    const int d = idx & (DDIM - 1);
    const int rest = idx >> 8;
    const int chunk = rest & (NCHUNK - 1);
    const int b = rest >> 6;

    size_t base = ((size_t)b * TDIM + (size_t)chunk * LCHUNK) * DDIM + d;
    float A = 1.0f, c = 0.0f;
    for (int i = 0; i < LCHUNK; ++i) {
        const float f = fbuf[base];
        const float z = zbuf[base];
        A *= f;
        c = f * c + (1.0f - f) * z;
        base += DDIM;
    }
    aggA[idx] = A;
    aggB[idx] = c;
}

// ---------------------------------------------------------------------------
// Kernel 3: sequential carry scan across chunks (tiny: B*D = 2048 threads).
// carry[b,chunk,d] = c entering that chunk.
// ---------------------------------------------------------------------------
__global__ __launch_bounds__(256) void carry_scan(
    const float* __restrict__ aggA, const float* __restrict__ aggB,
    float* __restrict__ carry)
{
    const int idx = blockIdx.x * 256 + threadIdx.x;  // b*256 + d
    const int d = idx & (DDIM - 1);
    const int b = idx >> 8;
    float c = 0.0f;
    for (int ch = 0; ch < NCHUNK; ++ch) {
        const size_t p = ((size_t)b * NCHUNK + ch) * DDIM + d;
        const float A = aggA[p];
        const float Bv = aggB[p];
        carry[p] = c;
        c = A * c + Bv;
    }
}

// ---------------------------------------------------------------------------
// Kernel 4: scan pass 2 — replay chunk with true carry, emit h = o * c.
// o was staged in d_out; overwritten in place by h (same thread, same addr).
// ---------------------------------------------------------------------------
__global__ __launch_bounds__(256) void scan_pass2(
    const float* __restrict__ zbuf, const float* __restrict__ fbuf,
    float* __restrict__ obuf_h, const float* __restrict__ carry)
{
    const int idx = blockIdx.x * 256 + threadIdx.x;
    const int d = idx & (DDIM - 1);
    const int rest = idx >> 8;
    const int chunk = rest & (NCHUNK - 1);
    const int b = rest >> 6;

    size_t base = ((size_t)b * TDIM + (size_t)chunk * LCHUNK) * DDIM + d;
    float c = carry[idx];
    for (int i = 0; i < LCHUNK; ++i) {
        const float f = fbuf[base];
        const float z = zbuf[base];
        const float o = obuf_h[base];
        c = f * c + (1.0f - f) * z;
        obuf_h[base] = o * c;
        base += DDIM;
    }
}

extern "C" void kernel_launch(void* const* d_in, const int* in_sizes, int n_in,
                              void* d_out, int out_size, void* d_ws, size_t ws_size,
                              hipStream_t stream)
{
    const float* x  = (const float*)d_in[0];
    const float* Wz = (const float*)d_in[1];
    const float* Wf = (const float*)d_in[2];
    const float* Wo = (const float*)d_in[3];
    const float* bz = (const float*)d_in[4];
    const float* bf = (const float*)d_in[5];
    const float* bo = (const float*)d_in[6];
    float* out = (float*)d_out;

    // Workspace layout (floats): z[M*D] | f[M*D] | aggA | aggB | carry
    float* zbuf = (float*)d_ws;
    float* fbuf = zbuf + (size_t)MDIM * DDIM;
    float* aggA = fbuf + (size_t)MDIM * DDIM;
    float* aggB = aggA + (size_t)BDIM * NCHUNK * DDIM;
    float* carry = aggB + (size_t)BDIM * NCHUNK * DDIM;

    // 1) gates: z,f -> ws ; o -> d_out (staged)
    dim3 ggrid(MDIM / 64, DDIM / 64, 3);
    gates_gemm<<<ggrid, 256, 0, stream>>>(x, Wz, Wf, Wo, bz, bf, bo,
                                          zbuf, fbuf, out);

    // 2) per-chunk aggregates
    const int nlanes = BDIM * NCHUNK * DDIM;  // 131072
    scan_pass1<<<nlanes / 256, 256, 0, stream>>>(zbuf, fbuf, aggA, aggB);

    // 3) carry scan across chunks
    carry_scan<<<(BDIM * DDIM) / 256, 256, 0, stream>>>(aggA, aggB, carry);

    // 4) replay with carry, write h into d_out
    scan_pass2<<<nlanes / 256, 256, 0, stream>>>(zbuf, fbuf, out, carry);
}

// Round 2
// 244.757 us; speedup vs baseline: 1.9005x; 1.9005x over previous
//
#include <hip/hip_runtime.h>
#include <hip/hip_bf16.h>
#include <hip/hip_fp16.h>

// Problem constants (B=8, T=4096, Din=Dout=256, WINDOW=2)
#define BDIM 8
#define TDIM 4096
#define DDIM 256
#define MDIM (BDIM * TDIM)      // 32768
#define NCHUNK 128              // chunks along T for the parallel scan
#define LCHUNK (TDIM / NCHUNK)  // 32

typedef _Float16 f16x8 __attribute__((ext_vector_type(8)));
typedef float f32x4 __attribute__((ext_vector_type(4)));

__device__ __forceinline__ float sigmoid_(float x) {
    return 1.0f / (1.0f + __expf(-x));
}
__device__ __forceinline__ float tanh_(float x) {
    return 2.0f / (1.0f + __expf(-2.0f * x)) - 1.0f;
}

#define GLOAD_LDS16(g, l)                                                    \
    __builtin_amdgcn_global_load_lds(                                        \
        (const __attribute__((address_space(1))) void*)(g),                  \
        (__attribute__((address_space(3))) void*)(l), 16, 0, 0)

// ---------------------------------------------------------------------------
// x [B,T,D] fp32 -> xpad [B,T+1,D] f16 with a zero row at t'=0.
// This linearizes the window-2 causal conv: row m=(b,t) of the GEMM A-matrix
// is the contiguous 512 halves starting at xpad[b][t][0].
// ---------------------------------------------------------------------------
__global__ __launch_bounds__(256) void convert_x(const float* __restrict__ x,
                                                 _Float16* __restrict__ xpad) {
    const int tp = blockIdx.x;  // 0..4096
    const int b = blockIdx.y;
    const int d = threadIdx.x;
    float v = 0.0f;
    if (tp > 0) v = x[((size_t)b * TDIM + tp - 1) * DDIM + d];
    xpad[((size_t)b * (TDIM + 1) + tp) * DDIM + d] = (_Float16)v;
}

// ---------------------------------------------------------------------------
// W[g][w][kin][n] fp32 -> Wt[g][n][w*256+kin] f16 (transposed so B-fragments
// are contiguous in k for ds_read_b128).
// ---------------------------------------------------------------------------
__global__ __launch_bounds__(256) void convert_w(
    const float* __restrict__ Wz, const float* __restrict__ Wf,
    const float* __restrict__ Wo, _Float16* __restrict__ Wt) {
    const int idx = blockIdx.x * 256 + threadIdx.x;  // < 3*2*256*256 = 393216
    const int n = idx & 255;
    const int kin = (idx >> 8) & 255;
    const int w = (idx >> 16) & 1;
    const int g = idx >> 17;
    const float* W = (g == 0) ? Wz : (g == 1) ? Wf : Wo;
    const float v = W[(size_t)w * 65536 + (size_t)kin * 256 + n];
    Wt[((size_t)g * 256 + n) * 512 + w * 256 + kin] = (_Float16)v;
}

// ---------------------------------------------------------------------------
// MFMA GEMM: gate[m,n] = act(bias[n] + A[m,:] @ Wt[gate][n,:]) with A from
// xpad (K=512 contiguous). 128x128 tile, 256 threads = 4 waves, each wave a
// 64x64 sub-tile as 4x4 frags of mfma_f32_16x16x32_f16. global_load_lds
// width-16 staging (m97 structure).
// z -> f16 zbuf ; f -> f16 fbuf ; o -> fp32 d_out (staged, later h in-place)
// ---------------------------------------------------------------------------
__global__ __launch_bounds__(256) void gates_mfma(
    const _Float16* __restrict__ xpad, const _Float16* __restrict__ Wt,
    const float* __restrict__ bz, const float* __restrict__ bfv,
    const float* __restrict__ bo,
    _Float16* __restrict__ zbuf, _Float16* __restrict__ fbuf,
    float* __restrict__ obuf) {
    const int gate = blockIdx.z;
    const int m0 = blockIdx.x * 128;
    const int n0 = blockIdx.y * 128;
    const int tid = threadIdx.x;
    const int lane = tid & 63;
    const int wave = tid >> 6;
    const int wr = wave >> 1;  // wave row (0..1)
    const int wc = wave & 1;   // wave col (0..1)

    __shared__ _Float16 As[128 * 32];  // [row][k] 64B rows
    __shared__ _Float16 Bs[128 * 32];  // [n][k]   64B rows

    // Staging: segment s handles row s>>2, k-bytes (s&3)*16.
    const int s = wave * 64 + lane;  // 0..255 (rows 0..63); +256 → rows 64..127
    const int r1 = s >> 2;
    const int kc = (s & 3) * 8;  // in halves

    const int b = m0 >> 12;          // batch of this tile (tiles never straddle)
    const int t0 = m0 & (TDIM - 1);

    const _Float16* srcA1 =
        xpad + ((size_t)b * (TDIM + 1) + t0 + r1) * DDIM + kc;
    const _Float16* srcA2 = srcA1 + (size_t)64 * DDIM;
    const _Float16* srcB1 = Wt + ((size_t)gate * 256 + n0 + r1) * 512 + kc;
    const _Float16* srcB2 = srcB1 + (size_t)64 * 512;

    char* dA1 = (char*)As + wave * 1024;
    char* dA2 = (char*)As + 4096 + wave * 1024;
    char* dB1 = (char*)Bs + wave * 1024;
    char* dB2 = (char*)Bs + 4096 + wave * 1024;

    f32x4 acc[4][4] = {};

    const int am = lane & 15;        // frag row/col within 16
    const int kq = (lane >> 4) * 8;  // k-quad offset in halves

    for (int k0 = 0; k0 < 512; k0 += 32) {
        __syncthreads();  // previous iter's LDS reads done
        GLOAD_LDS16(srcA1 + k0, dA1);
        GLOAD_LDS16(srcA2 + k0, dA2);
        GLOAD_LDS16(srcB1 + k0, dB1);
        GLOAD_LDS16(srcB2 + k0, dB2);
        __syncthreads();  // staging drained (vmcnt(0) before s_barrier)

        f16x8 a[4], bb[4];
#pragma unroll
        for (int i = 0; i < 4; ++i)
            a[i] = *(const f16x8*)(As + (wr * 64 + i * 16 + am) * 32 + kq);
#pragma unroll
        for (int j = 0; j < 4; ++j)
            bb[j] = *(const f16x8*)(Bs + (wc * 64 + j * 16 + am) * 32 + kq);
#pragma unroll
        for (int i = 0; i < 4; ++i)
#pragma unroll
            for (int j = 0; j < 4; ++j)
                acc[i][j] = __builtin_amdgcn_mfma_f32_16x16x32_f16(
                    a[i], bb[j], acc[i][j], 0, 0, 0);
    }

    // Epilogue. C/D layout: col = lane&15, row = (lane>>4)*4 + reg.
    const float* bias = (gate == 0) ? bz : (gate == 1) ? bfv : bo;
    const int rq = (lane >> 4) * 4;
#pragma unroll
    for (int j = 0; j < 4; ++j) {
        const int gc = n0 + wc * 64 + j * 16 + am;
        const float bj = bias[gc];
#pragma unroll
        for (int i = 0; i < 4; ++i) {
            const int gr0 = m0 + wr * 64 + i * 16 + rq;
            f32x4 v = acc[i][j];
#pragma unroll
            for (int r = 0; r < 4; ++r) {
                const float val = v[r] + bj;
                const size_t off = (size_t)(gr0 + r) * DDIM + gc;
                if (gate == 0)
                    zbuf[off] = (_Float16)tanh_(val);
                else if (gate == 1)
                    fbuf[off] = (_Float16)sigmoid_(val);
                else
                    obuf[off] = sigmoid_(val);
            }
        }
    }
}

// ---------------------------------------------------------------------------
// Scan pass 1: per-chunk aggregates over LCHUNK steps from c=0; A = prod(f).
// Thread handles 8 consecutive d (one 16B f16 vector per tensor per step).
// ---------------------------------------------------------------------------
__global__ __launch_bounds__(256) void scan_pass1(
    const _Float16* __restrict__ zbuf, const _Float16* __restrict__ fbuf,
    float* __restrict__ aggA, float* __restrict__ aggB) {
    const int idx = blockIdx.x * 256 + threadIdx.x;  // < B*NCHUNK*32 = 32768
    const int d8 = idx & 31;
    const int chunk = (idx >> 5) & (NCHUNK - 1);
    const int b = idx >> 12;

    const size_t row0 = (size_t)b * TDIM + (size_t)chunk * LCHUNK;
    const int4* zp = (const int4*)zbuf + row0 * 32 + d8;
    const int4* fp = (const int4*)fbuf + row0 * 32 + d8;

    float A[8], c[8];
#pragma unroll
    for (int e = 0; e < 8; ++e) { A[e] = 1.0f; c[e] = 0.0f; }

    for (int i = 0; i < LCHUNK; ++i) {
        int4 fv = *fp;
        int4 zv = *zp;
        const _Float16* fh = (const _Float16*)&fv;
        const _Float16* zh = (const _Float16*)&zv;
#pragma unroll
        for (int e = 0; e < 8; ++e) {
            const float f = (float)fh[e];
            const float z = (float)zh[e];
            A[e] *= f;
            c[e] = f * c[e] + (1.0f - f) * z;
        }
        fp += 32;
        zp += 32;
    }
    float4* aA = (float4*)aggA;
    float4* aB = (float4*)aggB;
    aA[(size_t)idx * 2 + 0] = make_float4(A[0], A[1], A[2], A[3]);
    aA[(size_t)idx * 2 + 1] = make_float4(A[4], A[5], A[6], A[7]);
    aB[(size_t)idx * 2 + 0] = make_float4(c[0], c[1], c[2], c[3]);
    aB[(size_t)idx * 2 + 1] = make_float4(c[4], c[5], c[6], c[7]);
}

// ---------------------------------------------------------------------------
// Carry scan across chunks: 256 threads, each owns 8 d's of one batch row.
// ---------------------------------------------------------------------------
__global__ __launch_bounds__(256) void carry_scan(
    const float* __restrict__ aggA, const float* __restrict__ aggB,
    float* __restrict__ carry) {
    const int idx = threadIdx.x;  // < B*32 = 256
    const int d8 = idx & 31;
    const int b = idx >> 5;
    float c[8];
#pragma unroll
    for (int e = 0; e < 8; ++e) c[e] = 0.0f;

    for (int ch = 0; ch < NCHUNK; ++ch) {
        const size_t p = ((size_t)(b * NCHUNK + ch) * 32 + d8) * 2;  // float4 units
        float4 A0 = ((const float4*)aggA)[p];
        float4 A1 = ((const float4*)aggA)[p + 1];
        float4 B0 = ((const float4*)aggB)[p];
        float4 B1 = ((const float4*)aggB)[p + 1];
        ((float4*)carry)[p] = make_float4(c[0], c[1], c[2], c[3]);
        ((float4*)carry)[p + 1] = make_float4(c[4], c[5], c[6], c[7]);
        c[0] = A0.x * c[0] + B0.x;
        c[1] = A0.y * c[1] + B0.y;
        c[2] = A0.z * c[2] + B0.z;
        c[3] = A0.w * c[3] + B0.w;
        c[4] = A1.x * c[4] + B1.x;
        c[5] = A1.y * c[5] + B1.y;
        c[6] = A1.z * c[6] + B1.z;
        c[7] = A1.w * c[7] + B1.w;
    }
}

// ---------------------------------------------------------------------------
// Scan pass 2: replay chunk with true carry, h = o*c written in place over o.
// ---------------------------------------------------------------------------
__global__ __launch_bounds__(256) void scan_pass2(
    const _Float16* __restrict__ zbuf, const _Float16* __restrict__ fbuf,
    const float* __restrict__ carry, float* __restrict__ out) {
    const int idx = blockIdx.x * 256 + threadIdx.x;
    const int d8 = idx & 31;
    const int chunk = (idx >> 5) & (NCHUNK - 1);
    const int b = idx >> 12;

    float c[8];
    float4 c0 = ((const float4*)carry)[(size_t)idx * 2];
    float4 c1 = ((const float4*)carry)[(size_t)idx * 2 + 1];
    c[0] = c0.x; c[1] = c0.y; c[2] = c0.z; c[3] = c0.w;
    c[4] = c1.x; c[5] = c1.y; c[6] = c1.z; c[7] = c1.w;

    const size_t row0 = (size_t)b * TDIM + (size_t)chunk * LCHUNK;
    const int4* zp = (const int4*)zbuf + row0 * 32 + d8;
    const int4* fp = (const int4*)fbuf + row0 * 32 + d8;
    float4* op = (float4*)out + row0 * 64 + d8 * 2;

    for (int i = 0; i < LCHUNK; ++i) {
        int4 fv = *fp;
        int4 zv = *zp;
        float4 o0 = op[0];
        float4 o1 = op[1];
        const _Float16* fh = (const _Float16*)&fv;
        const _Float16* zh = (const _Float16*)&zv;
        float h[8];
        const float* ov = (const float*)&o0;
#pragma unroll
        for (int e = 0; e < 8; ++e) {
            const float f = (float)fh[e];
            const float z = (float)zh[e];
            c[e] = f * c[e] + (1.0f - f) * z;
        }
        h[0] = o0.x * c[0]; h[1] = o0.y * c[1];
        h[2] = o0.z * c[2]; h[3] = o0.w * c[3];
        h[4] = o1.x * c[4]; h[5] = o1.y * c[5];
        h[6] = o1.z * c[6]; h[7] = o1.w * c[7];
        (void)ov;
        op[0] = make_float4(h[0], h[1], h[2], h[3]);
        op[1] = make_float4(h[4], h[5], h[6], h[7]);
        fp += 32;
        zp += 32;
        op += 64;
    }
}

extern "C" void kernel_launch(void* const* d_in, const int* in_sizes, int n_in,
                              void* d_out, int out_size, void* d_ws,
                              size_t ws_size, hipStream_t stream) {
    const float* x = (const float*)d_in[0];
    const float* Wz = (const float*)d_in[1];
    const float* Wf = (const float*)d_in[2];
    const float* Wo = (const float*)d_in[3];
    const float* bz = (const float*)d_in[4];
    const float* bfv = (const float*)d_in[5];
    const float* bo = (const float*)d_in[6];
    float* out = (float*)d_out;

    // Workspace layout (bytes):
    //   xpad f16 [B][T+1][D] : 16,781,312
    //   Wt   f16 [3][256][512]: 786,432
    //   zbuf f16 [M][D]      : 16,777,216
    //   fbuf f16 [M][D]      : 16,777,216
    //   aggA/aggB/carry f32  : 3 x 1,048,576      total ~54.3 MB
    char* p = (char*)d_ws;
    _Float16* xpad = (_Float16*)p;            p += (size_t)BDIM * (TDIM + 1) * DDIM * 2;
    _Float16* Wt = (_Float16*)p;              p += (size_t)3 * 256 * 512 * 2;
    _Float16* zbuf = (_Float16*)p;            p += (size_t)MDIM * DDIM * 2;
    _Float16* fbuf = (_Float16*)p;            p += (size_t)MDIM * DDIM * 2;
    float* aggA = (float*)p;                  p += (size_t)BDIM * NCHUNK * DDIM * 4;
    float* aggB = (float*)p;                  p += (size_t)BDIM * NCHUNK * DDIM * 4;
    float* carry = (float*)p;

    // 1) conversions
    convert_x<<<dim3(TDIM + 1, BDIM), 256, 0, stream>>>(x, xpad);
    convert_w<<<(3 * 2 * 256 * 256) / 256, 256, 0, stream>>>(Wz, Wf, Wo, Wt);

    // 2) MFMA gates: z,f -> ws (f16); o -> d_out (fp32 staged)
    gates_mfma<<<dim3(MDIM / 128, DDIM / 128, 3), 256, 0, stream>>>(
        xpad, Wt, bz, bfv, bo, zbuf, fbuf, out);

    // 3) per-chunk aggregates
    scan_pass1<<<(BDIM * NCHUNK * 32) / 256, 256, 0, stream>>>(zbuf, fbuf,
                                                               aggA, aggB);

    // 4) carry scan across chunks (one block)
    carry_scan<<<1, 256, 0, stream>>>(aggA, aggB, carry);

    // 5) replay with carry, h = o*c into d_out
    scan_pass2<<<(BDIM * NCHUNK * 32) / 256, 256, 0, stream>>>(zbuf, fbuf,
                                                               carry, out);
}

// Round 3
// 174.645 us; speedup vs baseline: 2.6634x; 1.4015x over previous
//
#include <hip/hip_runtime.h>
#include <hip/hip_bf16.h>
#include <hip/hip_fp16.h>

// Problem constants (B=8, T=4096, Din=Dout=256, WINDOW=2)
#define BDIM 8
#define TDIM 4096
#define DDIM 256
#define MDIM (BDIM * TDIM)      // 32768
#define NCHUNK 256              // chunks along T for the parallel scan
#define LCHUNK (TDIM / NCHUNK)  // 16

typedef _Float16 f16x8 __attribute__((ext_vector_type(8)));
typedef _Float16 f16x4 __attribute__((ext_vector_type(4)));
typedef float f32x4 __attribute__((ext_vector_type(4)));

__device__ __forceinline__ float sigmoid_(float x) {
    return 1.0f / (1.0f + __expf(-x));
}
__device__ __forceinline__ float tanh_(float x) {
    return 2.0f / (1.0f + __expf(-2.0f * x)) - 1.0f;
}

#define GLOAD_LDS16(g, l)                                                    \
    __builtin_amdgcn_global_load_lds(                                        \
        (const __attribute__((address_space(1))) void*)(g),                  \
        (__attribute__((address_space(3))) void*)(l), 16, 0, 0)

// ---------------------------------------------------------------------------
// x [B,T,D] fp32 -> xpad [B,T+1,D] f16 with a zero row at t'=0.
// One wave per (b, t') row; float4 reads (16 B/lane), 8 B/lane stores.
// ---------------------------------------------------------------------------
__global__ __launch_bounds__(64) void convert_x(const float* __restrict__ x,
                                                _Float16* __restrict__ xpad) {
    const int tp = blockIdx.x;  // 0..4096
    const int b = blockIdx.y;
    const int q = threadIdx.x;  // 0..63 -> 4 floats each
    float4 v = make_float4(0.f, 0.f, 0.f, 0.f);
    if (tp > 0)
        v = *(const float4*)(x + ((size_t)b * TDIM + tp - 1) * DDIM + q * 4);
    f16x4 h;
    h[0] = (_Float16)v.x; h[1] = (_Float16)v.y;
    h[2] = (_Float16)v.z; h[3] = (_Float16)v.w;
    *(f16x4*)(xpad + ((size_t)b * (TDIM + 1) + tp) * DDIM + q * 4) = h;
}

// ---------------------------------------------------------------------------
// W[g][w][kin][n] fp32 -> Wt[g][n][w*256+kin] f16 (contiguous in k).
// ---------------------------------------------------------------------------
__global__ __launch_bounds__(256) void convert_w(
    const float* __restrict__ Wz, const float* __restrict__ Wf,
    const float* __restrict__ Wo, _Float16* __restrict__ Wt) {
    const int idx = blockIdx.x * 256 + threadIdx.x;  // < 3*2*256*256
    const int n = idx & 255;
    const int kin = (idx >> 8) & 255;
    const int w = (idx >> 16) & 1;
    const int g = idx >> 17;
    const float* W = (g == 0) ? Wz : (g == 1) ? Wf : Wo;
    const float v = W[(size_t)w * 65536 + (size_t)kin * 256 + n];
    Wt[((size_t)g * 256 + n) * 512 + w * 256 + kin] = (_Float16)v;
}

// ---------------------------------------------------------------------------
// MFMA GEMM, software-pipelined: LDS double buffer, prefetch global_load_lds
// for tile k+1 issued right after the single per-iteration barrier, so the
// vmcnt(0) drain at the NEXT barrier lands a full iteration later.
// 128x128 tile, 4 waves, 4x4 frags of mfma_f32_16x16x32_f16.
// Epilogue repacks through LDS so each lane stores 16 contiguous bytes.
// All three outputs (z,f,o) stored as f16.
// ---------------------------------------------------------------------------
__global__ __launch_bounds__(256) void gates_mfma(
    const _Float16* __restrict__ xpad, const _Float16* __restrict__ Wt,
    const float* __restrict__ bz, const float* __restrict__ bfv,
    const float* __restrict__ bo,
    _Float16* __restrict__ zbuf, _Float16* __restrict__ fbuf,
    _Float16* __restrict__ obuf) {
    const int gate = blockIdx.z;
    const int m0 = blockIdx.x * 128;
    const int n0 = blockIdx.y * 128;
    const int tid = threadIdx.x;
    const int lane = tid & 63;
    const int wave = tid >> 6;
    const int wr = wave >> 1;  // wave row (0..1)
    const int wc = wave & 1;   // wave col (0..1)

    // [0,16384): buf0 (A 8K | B 8K), [16384,32768): buf1.
    // Epilogue reuses [0,40960) as 4 x 10240 B per-wave repack tiles.
    __shared__ __align__(16) char smem[40960];

    // Staging: segment s = wave*64+lane handles row s>>2, 16-B k-chunk s&3.
    const int s = wave * 64 + lane;
    const int r1 = s >> 2;
    const int kc = (s & 3) * 8;  // halves

    const int b = m0 >> 12;
    const int t0 = m0 & (TDIM - 1);

    const _Float16* srcA1 =
        xpad + ((size_t)b * (TDIM + 1) + t0 + r1) * DDIM + kc;
    const _Float16* srcA2 = srcA1 + (size_t)64 * DDIM;
    const _Float16* srcB1 = Wt + ((size_t)gate * 256 + n0 + r1) * 512 + kc;
    const _Float16* srcB2 = srcB1 + (size_t)64 * 512;

    f32x4 acc[4][4] = {};
    const int am = lane & 15;
    const int kq = (lane >> 4) * 8;  // halves

    // Prologue: stage tile 0 into buf0.
    {
        char* dA = smem + wave * 1024;
        char* dB = smem + 8192 + wave * 1024;
        GLOAD_LDS16(srcA1, dA);
        GLOAD_LDS16(srcA2, dA + 4096);
        GLOAD_LDS16(srcB1, dB);
        GLOAD_LDS16(srcB2, dB + 4096);
    }

    for (int it = 0; it < 16; ++it) {
        __syncthreads();  // vmcnt(0): buf[it&1] staged; prev reads complete
        const int cur = it & 1;
        if (it < 15) {  // prefetch tile it+1 into the other buffer
            const int k1 = (it + 1) * 32;
            char* dA = smem + (cur ^ 1) * 16384 + wave * 1024;
            char* dB = smem + (cur ^ 1) * 16384 + 8192 + wave * 1024;
            GLOAD_LDS16(srcA1 + k1, dA);
            GLOAD_LDS16(srcA2 + k1, dA + 4096);
            GLOAD_LDS16(srcB1 + k1, dB);
            GLOAD_LDS16(srcB2 + k1, dB + 4096);
        }
        const _Float16* Ab = (const _Float16*)(smem + cur * 16384);
        const _Float16* Bb = (const _Float16*)(smem + cur * 16384 + 8192);

        f16x8 a[4], bb[4];
#pragma unroll
        for (int i = 0; i < 4; ++i)
            a[i] = *(const f16x8*)(Ab + (wr * 64 + i * 16 + am) * 32 + kq);
#pragma unroll
        for (int j = 0; j < 4; ++j)
            bb[j] = *(const f16x8*)(Bb + (wc * 64 + j * 16 + am) * 32 + kq);
#pragma unroll
        for (int i = 0; i < 4; ++i)
#pragma unroll
            for (int j = 0; j < 4; ++j)
                acc[i][j] = __builtin_amdgcn_mfma_f32_16x16x32_f16(
                    a[i], bb[j], acc[i][j], 0, 0, 0);
    }

    __syncthreads();  // all K-loop LDS reads done before epilogue reuse

    // Epilogue: activation into per-wave LDS tile (stride 80 halves = 160 B,
    // 16B-aligned rows), then 16 B/lane contiguous global stores.
    const float* bias = (gate == 0) ? bz : (gate == 1) ? bfv : bo;
    _Float16* outp = (gate == 0) ? zbuf : (gate == 1) ? fbuf : obuf;
    _Float16* eb = (_Float16*)smem + wave * 5120;  // 64 x 80 halves
    const int rq = (lane >> 4) * 4;
#pragma unroll
    for (int j = 0; j < 4; ++j) {
        const int gc = n0 + wc * 64 + j * 16 + am;
        const float bj = bias[gc];
#pragma unroll
        for (int i = 0; i < 4; ++i) {
            f32x4 v = acc[i][j];
#pragma unroll
            for (int r = 0; r < 4; ++r) {
                const float val = v[r] + bj;
                const float act = (gate == 0) ? tanh_(val) : sigmoid_(val);
                eb[(i * 16 + rq + r) * 80 + j * 16 + am] = (_Float16)act;
            }
        }
    }
    __syncthreads();  // wave-internal + uniform; ensures writes visible

    const int rrow = lane >> 3;       // 0..7
    const int rcol = (lane & 7) * 8;  // halves
#pragma unroll
    for (int rr = 0; rr < 8; ++rr) {
        const int row = rr * 8 + rrow;
        f16x8 v = *(const f16x8*)(eb + row * 80 + rcol);
        const size_t gm = (size_t)(m0 + wr * 64 + row);
        *(f16x8*)(outp + gm * DDIM + n0 + wc * 64 + rcol) = v;
    }
}

// ---------------------------------------------------------------------------
// Scan pass 1: per-chunk aggregates over LCHUNK steps from c=0; A = prod(f).
// 65536 lanes -> 256 blocks (all CUs). 16 B f16 vector loads.
// ---------------------------------------------------------------------------
__global__ __launch_bounds__(256) void scan_pass1(
    const _Float16* __restrict__ zbuf, const _Float16* __restrict__ fbuf,
    float* __restrict__ aggA, float* __restrict__ aggB) {
    const int idx = blockIdx.x * 256 + threadIdx.x;  // < B*NCHUNK*32 = 65536
    const int d8 = idx & 31;
    const int chunk = (idx >> 5) & (NCHUNK - 1);
    const int b = idx >> 13;

    const size_t row0 = (size_t)b * TDIM + (size_t)chunk * LCHUNK;
    const int4* zp = (const int4*)zbuf + row0 * 32 + d8;
    const int4* fp = (const int4*)fbuf + row0 * 32 + d8;

    float A[8], c[8];
#pragma unroll
    for (int e = 0; e < 8; ++e) { A[e] = 1.0f; c[e] = 0.0f; }

    for (int i = 0; i < LCHUNK; ++i) {
        int4 fv = *fp;
        int4 zv = *zp;
        const _Float16* fh = (const _Float16*)&fv;
        const _Float16* zh = (const _Float16*)&zv;
#pragma unroll
        for (int e = 0; e < 8; ++e) {
            const float f = (float)fh[e];
            const float z = (float)zh[e];
            A[e] *= f;
            c[e] = f * c[e] + (1.0f - f) * z;
        }
        fp += 32;
        zp += 32;
    }
    ((float4*)aggA)[(size_t)idx * 2 + 0] = make_float4(A[0], A[1], A[2], A[3]);
    ((float4*)aggA)[(size_t)idx * 2 + 1] = make_float4(A[4], A[5], A[6], A[7]);
    ((float4*)aggB)[(size_t)idx * 2 + 0] = make_float4(c[0], c[1], c[2], c[3]);
    ((float4*)aggB)[(size_t)idx * 2 + 1] = make_float4(c[4], c[5], c[6], c[7]);
}

// ---------------------------------------------------------------------------
// Carry scan across chunks: one thread per (b,d) = 2048 threads, unroll-8
// batched loads (16 outstanding) to hide latency over 256 serial chunks.
// agg layout: [b][chunk][d].
// ---------------------------------------------------------------------------
__global__ __launch_bounds__(256) void carry_scan(
    const float* __restrict__ aggA, const float* __restrict__ aggB,
    float* __restrict__ carry) {
    const int g = blockIdx.x * 256 + threadIdx.x;  // < B*D = 2048
    const int d = g & 255;
    const int b = g >> 8;
    const size_t base = (size_t)b * NCHUNK * 256 + d;

    float c = 0.0f;
    for (int ch0 = 0; ch0 < NCHUNK; ch0 += 8) {
        float A[8], Bv[8];
#pragma unroll
        for (int u = 0; u < 8; ++u) {
            const size_t p = base + (size_t)(ch0 + u) * 256;
            A[u] = aggA[p];
            Bv[u] = aggB[p];
        }
#pragma unroll
        for (int u = 0; u < 8; ++u) {
            const size_t p = base + (size_t)(ch0 + u) * 256;
            carry[p] = c;
            c = A[u] * c + Bv[u];
        }
    }
}

// ---------------------------------------------------------------------------
// Scan pass 2: replay chunk with true carry; h = o*c -> fp32 out.
// z,f,o all f16 (16 B vector loads); out written as 2x float4.
// ---------------------------------------------------------------------------
__global__ __launch_bounds__(256) void scan_pass2(
    const _Float16* __restrict__ zbuf, const _Float16* __restrict__ fbuf,
    const _Float16* __restrict__ obuf, const float* __restrict__ carry,
    float* __restrict__ out) {
    const int idx = blockIdx.x * 256 + threadIdx.x;  // < 65536
    const int d8 = idx & 31;
    const int chunk = (idx >> 5) & (NCHUNK - 1);
    const int b = idx >> 13;

    float c[8];
    float4 c0 = ((const float4*)carry)[(size_t)idx * 2];
    float4 c1 = ((const float4*)carry)[(size_t)idx * 2 + 1];
    c[0] = c0.x; c[1] = c0.y; c[2] = c0.z; c[3] = c0.w;
    c[4] = c1.x; c[5] = c1.y; c[6] = c1.z; c[7] = c1.w;

    const size_t row0 = (size_t)b * TDIM + (size_t)chunk * LCHUNK;
    const int4* zp = (const int4*)zbuf + row0 * 32 + d8;
    const int4* fp = (const int4*)fbuf + row0 * 32 + d8;
    const int4* op = (const int4*)obuf + row0 * 32 + d8;
    float4* hp = (float4*)out + row0 * 64 + d8 * 2;

    for (int i = 0; i < LCHUNK; ++i) {
        int4 fv = *fp;
        int4 zv = *zp;
        int4 ov = *op;
        const _Float16* fh = (const _Float16*)&fv;
        const _Float16* zh = (const _Float16*)&zv;
        const _Float16* oh = (const _Float16*)&ov;
        float h[8];
#pragma unroll
        for (int e = 0; e < 8; ++e) {
            const float f = (float)fh[e];
            const float z = (float)zh[e];
            c[e] = f * c[e] + (1.0f - f) * z;
            h[e] = (float)oh[e] * c[e];
        }
        hp[0] = make_float4(h[0], h[1], h[2], h[3]);
        hp[1] = make_float4(h[4], h[5], h[6], h[7]);
        fp += 32;
        zp += 32;
        op += 32;
        hp += 64;
    }
}

extern "C" void kernel_launch(void* const* d_in, const int* in_sizes, int n_in,
                              void* d_out, int out_size, void* d_ws,
                              size_t ws_size, hipStream_t stream) {
    const float* x = (const float*)d_in[0];
    const float* Wz = (const float*)d_in[1];
    const float* Wf = (const float*)d_in[2];
    const float* Wo = (const float*)d_in[3];
    const float* bz = (const float*)d_in[4];
    const float* bfv = (const float*)d_in[5];
    const float* bo = (const float*)d_in[6];
    float* out = (float*)d_out;

    // Workspace (bytes): xpad 16.78M | Wt 0.79M | z 16.78M | f 16.78M |
    // o 16.78M | aggA 2M | aggB 2M | carry 2M   -> ~74.7 MB
    char* p = (char*)d_ws;
    _Float16* xpad = (_Float16*)p;  p += (size_t)BDIM * (TDIM + 1) * DDIM * 2;
    _Float16* Wt = (_Float16*)p;    p += (size_t)3 * 256 * 512 * 2;
    _Float16* zbuf = (_Float16*)p;  p += (size_t)MDIM * DDIM * 2;
    _Float16* fbuf = (_Float16*)p;  p += (size_t)MDIM * DDIM * 2;
    _Float16* obuf = (_Float16*)p;  p += (size_t)MDIM * DDIM * 2;
    float* aggA = (float*)p;        p += (size_t)BDIM * NCHUNK * DDIM * 4;
    float* aggB = (float*)p;        p += (size_t)BDIM * NCHUNK * DDIM * 4;
    float* carry = (float*)p;

    convert_x<<<dim3(TDIM + 1, BDIM), 64, 0, stream>>>(x, xpad);
    convert_w<<<(3 * 2 * 256 * 256) / 256, 256, 0, stream>>>(Wz, Wf, Wo, Wt);

    gates_mfma<<<dim3(MDIM / 128, DDIM / 128, 3), 256, 0, stream>>>(
        xpad, Wt, bz, bfv, bo, zbuf, fbuf, obuf);

    scan_pass1<<<(BDIM * NCHUNK * 32) / 256, 256, 0, stream>>>(zbuf, fbuf,
                                                               aggA, aggB);
    carry_scan<<<(BDIM * DDIM) / 256, 256, 0, stream>>>(aggA, aggB, carry);
    scan_pass2<<<(BDIM * NCHUNK * 32) / 256, 256, 0, stream>>>(zbuf, fbuf,
                                                               obuf, carry, out);
}